// Round 3
// baseline (497.910 us; speedup 1.0000x reference)
//
#include <hip/hip_runtime.h>
#include <hip/hip_bf16.h>

#define FFT_N 8192
#define HWN 196
#define CCH 2048
#define BATCH 16
#define PBLK 14   // blocks per batch
#define PPER 14   // p values per block

// position j (digit-reversed storage after DIF radix-4 x6 + radix-2) -> frequency k
__device__ __forceinline__ int kof(int j) {
    return ((j >> 11) & 3) | (((j >> 9) & 3) << 2) | (((j >> 7) & 3) << 4) |
           (((j >> 5) & 3) << 6) | (((j >> 3) & 3) << 8) | (((j >> 1) & 3) << 10) |
           ((j & 1) << 12);
}
// frequency k -> position j
__device__ __forceinline__ int pof(int k) {
    return ((k & 3) << 11) | (((k >> 2) & 3) << 9) | (((k >> 4) & 3) << 7) |
           (((k >> 6) & 3) << 5) | (((k >> 8) & 3) << 3) | (((k >> 10) & 3) << 1) |
           ((k >> 12) & 1);
}

__device__ __forceinline__ void cmul_tw(float& xr, float& xi, int e,
                                        const float* wr, const float* wi) {
    float s = (e & 4096) ? -1.f : 1.f;
    e &= 4095;
    float cr = s * wr[e], ci = s * wi[e];
    float nr = xr * cr - xi * ci;
    float ni = xr * ci + xi * cr;
    xr = nr; xi = ni;
}

// in-place DIF FFT, natural input -> digit-reversed output (order given by kof)
__device__ __forceinline__ void fft8192(float* zr, float* zi,
                                        const float* wr, const float* wi, int tid) {
    // radix-4 passes: L = 8192,2048,512,128,32,8
    for (int L = FFT_N; L >= 8; L >>= 2) {
        int q4 = L >> 2;
        int tstep = FFT_N / L;
#pragma unroll 2
        for (int u = tid; u < FFT_N / 4; u += 1024) {
            int o = u & (q4 - 1);
            int base = ((u & ~(q4 - 1)) << 2) | o;
            int i0 = base, i1 = base + q4, i2 = base + 2 * q4, i3 = base + 3 * q4;
            float ar = zr[i0], ai = zi[i0], br = zr[i1], bi = zi[i1];
            float cr = zr[i2], ci = zi[i2], dr = zr[i3], di = zi[i3];
            float t0r = ar + cr, t0i = ai + ci, t1r = ar - cr, t1i = ai - ci;
            float t2r = br + dr, t2i = bi + di, t3r = br - dr, t3i = bi - di;
            float u0r = t0r + t2r, u0i = t0i + t2i;
            float u2r = t0r - t2r, u2i = t0i - t2i;
            float u1r = t1r + t3i, u1i = t1i - t3r;  // t1 - i*t3
            float u3r = t1r - t3i, u3i = t1i + t3r;  // t1 + i*t3
            int e = o * tstep;
            zr[i0] = u0r; zi[i0] = u0i;
            cmul_tw(u1r, u1i, e, wr, wi);     zr[i1] = u1r; zi[i1] = u1i;
            cmul_tw(u2r, u2i, 2 * e, wr, wi); zr[i2] = u2r; zi[i2] = u2i;
            cmul_tw(u3r, u3i, 3 * e, wr, wi); zr[i3] = u3r; zi[i3] = u3i;
        }
        __syncthreads();
    }
    // final radix-2 pass on adjacent pairs
#pragma unroll 4
    for (int u = tid; u < FFT_N / 2; u += 1024) {
        int i0 = 2 * u, i1 = 2 * u + 1;
        float ar = zr[i0], ai = zi[i0], br = zr[i1], bi = zi[i1];
        zr[i0] = ar + br; zi[i0] = ai + bi;
        zr[i1] = ar - br; zi[i1] = ai - bi;
    }
    __syncthreads();
}

__device__ __forceinline__ void init_twiddles(float* wr, float* wi, int tid) {
    const float w0 = -7.66990393942820573e-4f;  // -2*pi/8192
#pragma unroll
    for (int s = 0; s < 4; s++) {
        int e = tid + 1024 * s;
        float sv, cv;
        sincosf(w0 * (float)e, &sv, &cv);
        wr[e] = cv; wi[e] = sv;
    }
}

__global__ __launch_bounds__(1024) void cbp_fwd(
    const float* __restrict__ x, const int* __restrict__ h1,
    const int* __restrict__ h2, const int* __restrict__ s1,
    const int* __restrict__ s2, float2* __restrict__ acc) {
    __shared__ float zr[FFT_N], zi[FFT_N];
    __shared__ float wr[FFT_N / 2], wi[FFT_N / 2];
    int tid = threadIdx.x;
    int b = blockIdx.x / PBLK;
    int pb = blockIdx.x % PBLK;

    init_twiddles(wr, wi, tid);

    int c0 = tid, c1 = tid + 1024;
    int h1a = h1[c0], h2a = h2[c0], h1b = h1[c1], h2b = h2[c1];
    float g1a = (float)(2 * s1[c0] - 1), g2a = (float)(2 * s2[c0] - 1);
    float g1b = (float)(2 * s1[c1] - 1), g2b = (float)(2 * s2[c1] - 1);

    float accR[8], accI[8];
#pragma unroll
    for (int s = 0; s < 8; s++) { accR[s] = 0.f; accI[s] = 0.f; }

    const float* xb = x + (size_t)b * CCH * HWN + pb * PPER;

    for (int ip = 0; ip < PPER; ++ip) {
#pragma unroll
        for (int s = 0; s < 8; s++) {
            zr[tid + 1024 * s] = 0.f;
            zi[tid + 1024 * s] = 0.f;
        }
        __syncthreads();
        float v0 = xb[c0 * HWN + ip];
        float v1 = xb[c1 * HWN + ip];
        atomicAdd(&zr[h1a], g1a * v0);
        atomicAdd(&zi[h2a], g2a * v0);
        atomicAdd(&zr[h1b], g1b * v1);
        atomicAdd(&zi[h2b], g2b * v1);
        __syncthreads();

        fft8192(zr, zi, wr, wi, tid);

        // P[k] = -i/4 * (Z[k]^2 - conj(Z[N-k])^2), accumulated per position j
#pragma unroll
        for (int s = 0; s < 8; s++) {
            int j = tid + 1024 * s;
            int k = kof(j);
            int m = (FFT_N - k) & (FFT_N - 1);
            int j2 = pof(m);
            float ar = zr[j], ai = zi[j], br = zr[j2], bi = zi[j2];
            float Dr = (ar * ar - ai * ai) - (br * br - bi * bi);
            float Di = 2.f * (ar * ai + br * bi);
            accR[s] += 0.25f * Di;
            accI[s] -= 0.25f * Dr;
        }
        __syncthreads();
    }

    float2* ab = acc + (size_t)b * FFT_N;
#pragma unroll
    for (int s = 0; s < 8; s++) {
        int j = tid + 1024 * s;
        atomicAdd(&ab[j].x, accR[s]);
        atomicAdd(&ab[j].y, accI[s]);
    }
}

__global__ __launch_bounds__(1024) void cbp_inv(
    const float2* __restrict__ acc, float* __restrict__ out) {
    __shared__ float zr[FFT_N], zi[FFT_N];
    __shared__ float wr[FFT_N / 2], wi[FFT_N / 2];
    __shared__ float red[20];
    int tid = threadIdx.x;
    int b = blockIdx.x;

    init_twiddles(wr, wi, tid);

    const float2* ab = acc + (size_t)b * FFT_N;
    // IFFT(P) = conj(FFT(conj(P)))/N; load conj(P) in natural frequency order
#pragma unroll
    for (int s = 0; s < 8; s++) {
        int j = tid + 1024 * s;
        float2 v = ab[j];
        int k = kof(j);
        zr[k] = v.x;
        zi[k] = -v.y;
    }
    __syncthreads();

    fft8192(zr, zi, wr, wi, tid);

    float sv[8];
    float ss = 0.f;
#pragma unroll
    for (int s = 0; s < 8; s++) {
        int j = tid + 1024 * s;
        float v = zr[j] * (1.f / (float)FFT_N);
        float r = copysignf(sqrtf(fabsf(v) + 1e-5f), v);
        sv[s] = r;
        ss += r * r;
    }
    // block reduction of ss
#pragma unroll
    for (int m = 32; m >= 1; m >>= 1) ss += __shfl_xor(ss, m);
    int wave = tid >> 6, lane = tid & 63;
    if (lane == 0) red[wave] = ss;
    __syncthreads();
    if (tid == 0) {
        float tot = 0.f;
        for (int w = 0; w < 16; w++) tot += red[w];
        red[16] = fmaxf(sqrtf(tot), 1e-12f);
    }
    __syncthreads();
    float inv = 1.f / red[16];
    float* ob = out + (size_t)b * FFT_N;
#pragma unroll
    for (int s = 0; s < 8; s++) {
        int j = tid + 1024 * s;
        ob[kof(j)] = sv[s] * inv;
    }
}

extern "C" void kernel_launch(void* const* d_in, const int* in_sizes, int n_in,
                              void* d_out, int out_size, void* d_ws, size_t ws_size,
                              hipStream_t stream) {
    const float* x = (const float*)d_in[0];
    const int* h1 = (const int*)d_in[1];
    const int* h2 = (const int*)d_in[2];
    const int* s1 = (const int*)d_in[3];
    const int* s2 = (const int*)d_in[4];
    float* out = (float*)d_out;
    float2* acc = (float2*)d_ws;

    hipMemsetAsync(acc, 0, (size_t)BATCH * FFT_N * sizeof(float2), stream);
    cbp_fwd<<<BATCH * PBLK, 1024, 0, stream>>>(x, h1, h2, s1, s2, acc);
    cbp_inv<<<BATCH, 1024, 0, stream>>>(acc, (float*)out);
}

// Round 5
// 321.105 us; speedup vs baseline: 1.5506x; 1.5506x over previous
//
#include <hip/hip_runtime.h>
#include <hip/hip_bf16.h>
#include <math.h>

#define FFT_N 8192
#define HWN 196
#define CCH 2048
#define BATCH 16
#define PBLK 14   // blocks per batch
#define PPER 14   // p values per block

// position j (digit-reversed storage after DIF radix-4 x6 + radix-2) -> frequency k
__device__ __forceinline__ int kof(int j) {
    return ((j >> 11) & 3) | (((j >> 9) & 3) << 2) | (((j >> 7) & 3) << 4) |
           (((j >> 5) & 3) << 6) | (((j >> 3) & 3) << 8) | (((j >> 1) & 3) << 10) |
           ((j & 1) << 12);
}
// frequency k -> position j
__device__ __forceinline__ int pof(int k) {
    return ((k & 3) << 11) | (((k >> 2) & 3) << 9) | (((k >> 4) & 3) << 7) |
           (((k >> 6) & 3) << 5) | (((k >> 8) & 3) << 3) | (((k >> 10) & 3) << 1) |
           ((k >> 12) & 1);
}

// per-pass twiddle tables, stride-1 indexed by o: T[OFF+o] = exp(-2*pi*i*o*tstep/N)
// sizes: q4=2048:2048 @0, 512 @2048, 128 @2560, 32 @2688, 8 @2720, 2 @2728; total 2730
#define TW_TOTAL 2730

__device__ __forceinline__ float2 cmul(float2 a, float2 b) {
    return make_float2(a.x * b.x - a.y * b.y, a.x * b.y + a.y * b.x);
}

template <int Q4, int OFF>
__device__ __forceinline__ void pass4(float2* z, const float2* T, int tid) {
#pragma unroll
    for (int it = 0; it < FFT_N / 4 / 1024; ++it) {
        int u = tid + 1024 * it;
        int o = u & (Q4 - 1);
        int base = ((u & ~(Q4 - 1)) << 2) | o;
        float2 a = z[base], b = z[base + Q4], c = z[base + 2 * Q4], d = z[base + 3 * Q4];
        float t0r = a.x + c.x, t0i = a.y + c.y, t1r = a.x - c.x, t1i = a.y - c.y;
        float t2r = b.x + d.x, t2i = b.y + d.y, t3r = b.x - d.x, t3i = b.y - d.y;
        float2 u0 = make_float2(t0r + t2r, t0i + t2i);
        float2 u2 = make_float2(t0r - t2r, t0i - t2i);
        float2 u1 = make_float2(t1r + t3i, t1i - t3r);  // t1 - i*t3
        float2 u3 = make_float2(t1r - t3i, t1i + t3r);  // t1 + i*t3
        float2 w1 = T[OFF + o];
        float2 w2 = make_float2(w1.x * w1.x - w1.y * w1.y, 2.f * w1.x * w1.y);
        float2 w3 = cmul(w1, w2);
        z[base] = u0;
        z[base + Q4] = cmul(u1, w1);
        z[base + 2 * Q4] = cmul(u2, w2);
        z[base + 3 * Q4] = cmul(u3, w3);
    }
    __syncthreads();
}

// in-place DIF FFT, natural input -> digit-reversed output (order given by kof)
__device__ __forceinline__ void fft8192(float2* z, const float2* T, int tid) {
    pass4<2048, 0>(z, T, tid);
    pass4<512, 2048>(z, T, tid);
    pass4<128, 2560>(z, T, tid);
    pass4<32, 2688>(z, T, tid);
    pass4<8, 2720>(z, T, tid);
    pass4<2, 2728>(z, T, tid);
    // final radix-2 pass on adjacent pairs
#pragma unroll
    for (int it = 0; it < 4; ++it) {
        int u = tid + 1024 * it;
        int i0 = 2 * u, i1 = 2 * u + 1;
        float2 a = z[i0], b = z[i1];
        z[i0] = make_float2(a.x + b.x, a.y + b.y);
        z[i1] = make_float2(a.x - b.x, a.y - b.y);
    }
    __syncthreads();
}

__device__ __forceinline__ void build_tables(float2* T, int tid) {
    const float w0 = -7.66990393942820573e-4f;  // -2*pi/8192
    for (int o = tid; o < 2048; o += 1024) {    // tstep 1
        float s, c; sincosf(w0 * (float)o, &s, &c); T[o] = make_float2(c, s);
    }
    if (tid < 512) {  // tstep 4
        float s, c; sincosf(w0 * (float)(tid * 4), &s, &c); T[2048 + tid] = make_float2(c, s);
    }
    if (tid < 128) {  // tstep 16
        float s, c; sincosf(w0 * (float)(tid * 16), &s, &c); T[2560 + tid] = make_float2(c, s);
    }
    if (tid < 32) {   // tstep 64
        float s, c; sincosf(w0 * (float)(tid * 64), &s, &c); T[2688 + tid] = make_float2(c, s);
    }
    if (tid < 8) {    // tstep 256
        float s, c; sincosf(w0 * (float)(tid * 256), &s, &c); T[2720 + tid] = make_float2(c, s);
    }
    if (tid < 2) {    // tstep 1024
        float s, c; sincosf(w0 * (float)(tid * 1024), &s, &c); T[2728 + tid] = make_float2(c, s);
    }
}

__global__ __launch_bounds__(1024) void cbp_fwd(
    const float* __restrict__ x, const int* __restrict__ h1,
    const int* __restrict__ h2, const int* __restrict__ s1,
    const int* __restrict__ s2, float2* __restrict__ acc) {
    __shared__ float2 z[FFT_N];
    __shared__ float2 T[TW_TOTAL];
    int tid = threadIdx.x;
    int b = blockIdx.x / PBLK;
    int pb = blockIdx.x % PBLK;

    build_tables(T, tid);

    int c0 = tid, c1 = tid + 1024;
    int h1a = h1[c0], h2a = h2[c0], h1b = h1[c1], h2b = h2[c1];
    float g1a = (float)(2 * s1[c0] - 1), g2a = (float)(2 * s2[c0] - 1);
    float g1b = (float)(2 * s1[c1] - 1), g2b = (float)(2 * s2[c1] - 1);

    float accR[8], accI[8];
#pragma unroll
    for (int s = 0; s < 8; s++) { accR[s] = 0.f; accI[s] = 0.f; }

    const float* xa = x + (size_t)b * CCH * HWN + (size_t)c0 * HWN + pb * PPER;
    const float* xc = x + (size_t)b * CCH * HWN + (size_t)c1 * HWN + pb * PPER;

    float v0 = xa[0];
    float v1 = xc[0];

    for (int ip = 0; ip < PPER; ++ip) {
        // prefetch next position's values (hidden under this FFT)
        float nv0 = 0.f, nv1 = 0.f;
        if (ip + 1 < PPER) { nv0 = xa[ip + 1]; nv1 = xc[ip + 1]; }

#pragma unroll
        for (int s = 0; s < 8; s++) z[tid + 1024 * s] = make_float2(0.f, 0.f);
        __syncthreads();
        atomicAdd(&z[h1a].x, g1a * v0);
        atomicAdd(&z[h2a].y, g2a * v0);
        atomicAdd(&z[h1b].x, g1b * v1);
        atomicAdd(&z[h2b].y, g2b * v1);
        __syncthreads();

        fft8192(z, T, tid);

        // P[k] = -i/4 * (Z[k]^2 - conj(Z[N-k])^2), accumulated per position j
#pragma unroll
        for (int s = 0; s < 8; s++) {
            int j = tid + 1024 * s;
            int k = kof(j);
            int m = (FFT_N - k) & (FFT_N - 1);
            int j2 = pof(m);
            float2 a = z[j], bz = z[j2];
            float Dr = (a.x * a.x - a.y * a.y) - (bz.x * bz.x - bz.y * bz.y);
            float Di = 2.f * (a.x * a.y + bz.x * bz.y);
            accR[s] += 0.25f * Di;
            accI[s] -= 0.25f * Dr;
        }
        __syncthreads();
        v0 = nv0; v1 = nv1;
    }

    float2* ab = acc + (size_t)b * FFT_N;
#pragma unroll
    for (int s = 0; s < 8; s++) {
        int j = tid + 1024 * s;
        atomicAdd(&ab[j].x, accR[s]);
        atomicAdd(&ab[j].y, accI[s]);
    }
}

__global__ __launch_bounds__(1024) void cbp_inv(
    const float2* __restrict__ acc, float* __restrict__ out) {
    __shared__ float2 z[FFT_N];
    __shared__ float2 T[TW_TOTAL];
    __shared__ float red[20];
    int tid = threadIdx.x;
    int b = blockIdx.x;

    build_tables(T, tid);

    const float2* ab = acc + (size_t)b * FFT_N;
    // IFFT(P) = conj(FFT(conj(P)))/N; load conj(P) in natural frequency order
#pragma unroll
    for (int s = 0; s < 8; s++) {
        int j = tid + 1024 * s;
        float2 v = ab[j];
        z[kof(j)] = make_float2(v.x, -v.y);
    }
    __syncthreads();

    fft8192(z, T, tid);

    float sv[8];
    float ss = 0.f;
#pragma unroll
    for (int s = 0; s < 8; s++) {
        int j = tid + 1024 * s;
        float v = z[j].x * (1.f / (float)FFT_N);
        float r = copysignf(sqrtf(fabsf(v) + 1e-5f), v);
        sv[s] = r;
        ss += r * r;
    }
    // block reduction of ss
#pragma unroll
    for (int m = 32; m >= 1; m >>= 1) ss += __shfl_xor(ss, m);
    int wave = tid >> 6, lane = tid & 63;
    if (lane == 0) red[wave] = ss;
    __syncthreads();
    if (tid == 0) {
        float tot = 0.f;
        for (int w = 0; w < 16; w++) tot += red[w];
        red[16] = fmaxf(sqrtf(tot), 1e-12f);
    }
    __syncthreads();
    float inv = 1.f / red[16];
    float* ob = out + (size_t)b * FFT_N;
#pragma unroll
    for (int s = 0; s < 8; s++) {
        int j = tid + 1024 * s;
        ob[kof(j)] = sv[s] * inv;
    }
}

extern "C" void kernel_launch(void* const* d_in, const int* in_sizes, int n_in,
                              void* d_out, int out_size, void* d_ws, size_t ws_size,
                              hipStream_t stream) {
    const float* x = (const float*)d_in[0];
    const int* h1 = (const int*)d_in[1];
    const int* h2 = (const int*)d_in[2];
    const int* s1 = (const int*)d_in[3];
    const int* s2 = (const int*)d_in[4];
    float* out = (float*)d_out;
    float2* acc = (float2*)d_ws;

    hipMemsetAsync(acc, 0, (size_t)BATCH * FFT_N * sizeof(float2), stream);
    cbp_fwd<<<BATCH * PBLK, 1024, 0, stream>>>(x, h1, h2, s1, s2, acc);
    cbp_inv<<<BATCH, 1024, 0, stream>>>(acc, (float*)out);
}